// Round 16
// baseline (179.006 us; speedup 1.0000x reference)
//
#include <hip/hip_runtime.h>

#define N_TOT  400000
#define NTILE  25000        // N_TOT / 16 voxels per tile
#define NELEM  (N_TOT * 16)
#define CBLK   512          // persistent conv blocks (2 per CU)
#define GS     (CBLK * 4)   // wave grid stride (tiles)

typedef __attribute__((ext_vector_type(8))) short short8;
typedef __attribute__((ext_vector_type(4))) float f32x4;
typedef __attribute__((ext_vector_type(4))) unsigned short us4;

__device__ __forceinline__ unsigned short f2bf(float x) {
    unsigned int u = __float_as_uint(x);
    u += 0x7FFFu + ((u >> 16) & 1u);       // round-to-nearest-even
    return (unsigned short)(u >> 16);
}
__device__ __forceinline__ float bf2f(unsigned short h) {
    return __uint_as_float(((unsigned int)h) << 16);
}

// Merged prep: blocks 0..3124 cvt f32->bf16; 3125..3194 build W-fragments for
// all 5 layers x 14 k-pairs (fragment (lane,slot)->element: lane l slot j ->
// W[2p+(l>>5)][((l>>4)&1)*8+j][l&15], used as the MFMA A-operand after the
// operand swap); block 3195 zeroes the pad voxel (index N_TOT) in xb/ob and
// the 5 per-layer S8 atomic-partial slots (replay-safe reset each launch).
__global__ __launch_bounds__(256) void prep_k(const float* __restrict__ vf,
                                              const float* __restrict__ w_in,
                                              const float* __restrict__ wbs,
                                              unsigned short* __restrict__ xb,
                                              unsigned short* __restrict__ ob,
                                              unsigned short* __restrict__ wfrag,
                                              unsigned long long* __restrict__ S8) {
    int b = blockIdx.x;
    if (b < 3125) {
        int i = (b * 256 + threadIdx.x) * 8;
        f32x4 a = *reinterpret_cast<const f32x4*>(vf + i);
        f32x4 c = *reinterpret_cast<const f32x4*>(vf + i + 4);
        short8 o = { (short)f2bf(a[0]), (short)f2bf(a[1]), (short)f2bf(a[2]), (short)f2bf(a[3]),
                     (short)f2bf(c[0]), (short)f2bf(c[1]), (short)f2bf(c[2]), (short)f2bf(c[3]) };
        *reinterpret_cast<short8*>(xb + i) = o;
    } else if (b < 3195) {
        if (threadIdx.x >= 64) return;
        int wb = b - 3125;               // L*14 + p
        int L = wb / 14, p = wb % 14;
        int l = threadIdx.x;
        int g = l >> 4, col = l & 15;
        int k = 2 * p + (g >> 1);
        int cib = (g & 1) * 8;
        unsigned short v[8];
#pragma unroll
        for (int j = 0; j < 8; ++j) {
            float w = 0.f;
            if (k < 27) {
                int ci = cib + j;
                w = (L == 0) ? w_in[(k * 16 + ci) * 16 + col]
                             : wbs[(((L - 1) * 27 + k) * 16 + ci) * 16 + col];
            }
            v[j] = f2bf(w);
        }
        unsigned short* dst = wfrag + (size_t)(wb * 64 + l) * 8;
#pragma unroll
        for (int j = 0; j < 8; ++j) dst[j] = v[j];
    } else {
        if (threadIdx.x < 8) {
            us4 z = {0, 0, 0, 0};
            unsigned short* base = (threadIdx.x < 4) ? xb : ob;
            reinterpret_cast<us4*>(base + NELEM)[threadIdx.x & 3] = z;
        }
        for (int i = threadIdx.x; i < 5 * 8 * 32; i += 256) S8[i] = 0ull;
    }
}

// Persistent gather-MFMA conv, 3-stage decoupled pipeline (champion structure):
//   idx loads tile t+2S | gathers tile t+S | MFMA+store tile t.
// nbr reads are NONTEMPORAL: the 41.6MB single-use index stream bypasses L2 so
// the 12.8MB feature buffer stays L2-resident for the scattered gathers.
// Operand swap: W = A-operand (registers), gathered features = B-operand ->
// each lane's 4 acc values are 4 contiguous CHANNELS of voxel rc -> single
// packed 8B store. Center (k=13) = identity (no load); invalid -> zero voxel
// at N_TOT (coalesced broadcast line). BN partials: per-channel lane
// accumulators, block-reduced, then 32 scaled-int64 atomicAdds (exact-
// commutative -> deterministic) into this layer's S8 slot. No reduce kernel.
#define IDX(I, tt)                                                              \
  {                                                                             \
    const int vv = (tt) * 16;                                                   \
    _Pragma("unroll")                                                           \
    for (int p = 0; p < 14; ++p) {                                              \
      int k = 2 * p + ksel;                                                     \
      if (k == 13)      I[p] = vv + rc;                                         \
      else if (k < 27)  I[p] = __builtin_nontemporal_load(                      \
                                   &nbr[(size_t)k * N_TOT + vv + rc]);          \
      else              I[p] = -1;                                              \
    }                                                                           \
  }

#define GAT(A, I)                                                               \
  {                                                                             \
    _Pragma("unroll")                                                           \
    for (int p = 0; p < 14; ++p) {                                              \
      int ci = I[p] < 0 ? N_TOT : I[p];                                         \
      A[p] = *reinterpret_cast<const short8*>(feats + ((size_t)ci << 4) + half);\
    }                                                                           \
  }

#define CMP(A, tt)                                                              \
  {                                                                             \
    f32x4 ac0 = {0.f, 0.f, 0.f, 0.f};                                           \
    f32x4 ac1 = {0.f, 0.f, 0.f, 0.f};                                           \
    _Pragma("unroll")                                                           \
    for (int p = 0; p < 14; p += 2) {                                           \
      ac0 = __builtin_amdgcn_mfma_f32_16x16x32_bf16(W[p],     A[p],     ac0, 0, 0, 0); \
      ac1 = __builtin_amdgcn_mfma_f32_16x16x32_bf16(W[p + 1], A[p + 1], ac1, 0, 0, 0); \
    }                                                                           \
    f32x4 acc = ac0 + ac1;                                                      \
    const int vv = (tt) * 16;                                                   \
    us4 pk = { f2bf(acc[0]), f2bf(acc[1]), f2bf(acc[2]), f2bf(acc[3]) };        \
    *reinterpret_cast<us4*>(raw + ((size_t)(vv + rc) * 16 + hi * 4)) = pk;      \
    _Pragma("unroll")                                                           \
    for (int i = 0; i < 4; ++i) {                                               \
      s_acc[i] += acc[i];                                                       \
      q_acc[i] += acc[i] * acc[i];                                              \
    }                                                                           \
  }

__global__ __launch_bounds__(256, 2) void conv_k(const unsigned short* __restrict__ feats,
                                                 const int* __restrict__ nbr,
                                                 const unsigned short* __restrict__ wfrag,
                                                 unsigned short* __restrict__ raw,
                                                 unsigned long long* __restrict__ S8) {
    __shared__ float red[128];

    const int lane = threadIdx.x & 63;
    const int wv   = threadIdx.x >> 6;
    const int hi   = lane >> 4;        // fragment k-block / output channel group
    const int rc   = lane & 15;        // voxel within tile
    const int half = (hi & 1) * 8;     // which 8 input channels this lane loads
    const int ksel = hi >> 1;          // which offset of the pair

    // loop-invariant W-fragments: 14 x short8 = 56 VGPRs, loaded once per wave
    short8 W[14];
#pragma unroll
    for (int p = 0; p < 14; ++p)
        W[p] = *reinterpret_cast<const short8*>(wfrag + (size_t)(p * 64 + lane) * 8);

    float s_acc[4] = {0.f, 0.f, 0.f, 0.f};
    float q_acc[4] = {0.f, 0.f, 0.f, 0.f};

    int I0[14], I1[14];
    short8 A0[14], A1[14];

    int t0 = blockIdx.x * 4 + wv;
    IDX(I0, t0);
    GAT(A0, I0);                       // one exposed stall at prologue
    int t1 = t0 + GS;
    if (t1 < NTILE) IDX(I1, t1);

    for (;;) {
        // invariant: A0 in flight for t0; I1 in flight/arrived for t1
        int t2 = t0 + 2 * GS;
        if (t2 < NTILE) IDX(I0, t2);
        if (t1 < NTILE) GAT(A1, I1);
        __builtin_amdgcn_sched_barrier(0);
        CMP(A0, t0);
        if (t1 >= NTILE) break;

        int t3 = t1 + 2 * GS;
        if (t3 < NTILE) IDX(I1, t3);
        if (t2 < NTILE) GAT(A0, I0);
        __builtin_amdgcn_sched_barrier(0);
        CMP(A1, t1);
        if (t2 >= NTILE) break;

        t0 = t2;
        t1 = t2 + GS;
    }

    // BN partials: lane (hi,rc) holds channels hi*4+i summed over its voxels;
    // reduce over rc within each 16-lane group, across waves via LDS, then 32
    // scaled-int64 atomics (8 shadow copies spread contention).
#pragma unroll
    for (int i = 0; i < 4; ++i) {
        s_acc[i] += __shfl_xor(s_acc[i], 1);  s_acc[i] += __shfl_xor(s_acc[i], 2);
        s_acc[i] += __shfl_xor(s_acc[i], 4);  s_acc[i] += __shfl_xor(s_acc[i], 8);
        q_acc[i] += __shfl_xor(q_acc[i], 1);  q_acc[i] += __shfl_xor(q_acc[i], 2);
        q_acc[i] += __shfl_xor(q_acc[i], 4);  q_acc[i] += __shfl_xor(q_acc[i], 8);
    }
    if (rc == 0) {
#pragma unroll
        for (int i = 0; i < 4; ++i) {
            red[wv * 32 + hi * 4 + i]      = s_acc[i];
            red[wv * 32 + 16 + hi * 4 + i] = q_acc[i];
        }
    }
    __syncthreads();
    if (threadIdx.x < 32) {
        float v = red[threadIdx.x] + red[32 + threadIdx.x] +
                  red[64 + threadIdx.x] + red[96 + threadIdx.x];
        long long qv = llrintf(v * (threadIdx.x < 16 ? 65536.0f : 16384.0f));
        atomicAdd(&S8[(blockIdx.x & 7) * 32 + threadIdx.x], (unsigned long long)qv);
    }
}

// BN finalize fused; sums the 8 S8 shadows inline, reads raw bf16 conv output,
// optional bf16 residual, writes bf16 features and/or f32 final output.
__global__ __launch_bounds__(256) void apply_k(const unsigned short* __restrict__ raw,
                                               const unsigned long long* __restrict__ S8,
                                               const float* __restrict__ gamma,
                                               const float* __restrict__ beta,
                                               const unsigned short* residb,
                                               unsigned short* bfout,
                                               float* f32out) {
    __shared__ float scs[16], shs[16];
    if (threadIdx.x < 16) {
        int c = threadIdx.x;
        long long ss = 0, qq = 0;
#pragma unroll
        for (int j = 0; j < 8; ++j) {
            ss += (long long)S8[j * 32 + c];
            qq += (long long)S8[j * 32 + 16 + c];
        }
        float s = (float)ss * (1.0f / 65536.0f);
        float q = (float)qq * (1.0f / 16384.0f);
        const float invN = 1.0f / (float)N_TOT;
        float m   = s * invN;
        float var = q * invN - m * m;
        float sc  = gamma[c] * rsqrtf(var + 1e-3f);
        scs[c] = sc;
        shs[c] = beta[c] - m * sc;
    }
    __syncthreads();
    int i = (blockIdx.x * 256 + threadIdx.x) * 8;
    int c0 = i & 8;                    // channels c0..c0+7
    short8 r8 = *reinterpret_cast<const short8*>(raw + i);
    float res[8] = {0, 0, 0, 0, 0, 0, 0, 0};
    if (residb) {
        short8 x8 = *reinterpret_cast<const short8*>(residb + i);
#pragma unroll
        for (int j = 0; j < 8; ++j) res[j] = bf2f((unsigned short)x8[j]);
    }
    float val[8];
#pragma unroll
    for (int j = 0; j < 8; ++j) {
        int c = c0 + j;
        val[j] = fmaxf(bf2f((unsigned short)r8[j]) * scs[c] + shs[c] + res[j], 0.f);
    }
    if (bfout) {
        short8 o = { (short)f2bf(val[0]), (short)f2bf(val[1]), (short)f2bf(val[2]), (short)f2bf(val[3]),
                     (short)f2bf(val[4]), (short)f2bf(val[5]), (short)f2bf(val[6]), (short)f2bf(val[7]) };
        *reinterpret_cast<short8*>(bfout + i) = o;
    }
    if (f32out) {
        f32x4 lo = { val[0], val[1], val[2], val[3] };
        f32x4 hi = { val[4], val[5], val[6], val[7] };
        *reinterpret_cast<f32x4*>(f32out + i)     = lo;
        *reinterpret_cast<f32x4*>(f32out + i + 4) = hi;
    }
}

extern "C" void kernel_launch(void* const* d_in, const int* in_sizes, int n_in,
                              void* d_out, int out_size, void* d_ws, size_t ws_size,
                              hipStream_t stream) {
    const float* vf   = (const float*)d_in[0];
    const int*   nbr  = (const int*)  d_in[1];
    const float* w_in = (const float*)d_in[2];
    const float* g_in = (const float*)d_in[3];
    const float* b_in = (const float*)d_in[4];
    const float* wbs  = (const float*)d_in[5];
    const float* gs   = (const float*)d_in[6];
    const float* bs   = (const float*)d_in[7];
    float* out = (float*)d_out;

    char* ws = (char*)d_ws;
    size_t off = 0;
    auto alloc = [&](size_t b) { char* p = ws + off; off += (b + 255) & ~(size_t)255; return p; };
    unsigned short*     wfrag = (unsigned short*)alloc((size_t)5 * 14 * 64 * 8 * 2);
    unsigned short*     xb    = (unsigned short*)alloc((size_t)(NELEM + 16) * 2);  // bf16 x (+zero voxel)
    unsigned short*     ob    = (unsigned short*)alloc((size_t)(NELEM + 16) * 2);  // bf16 o (+zero voxel)
    unsigned short*     rb    = (unsigned short*)alloc((size_t)NELEM * 2);         // bf16 raw conv out
    unsigned long long* S8    = (unsigned long long*)alloc((size_t)5 * 8 * 32 * 8);

    const int FR = 14 * 64 * 8;   // ushorts per layer of wfrag
    const int SL = 8 * 32;        // u64s per layer of S8

    prep_k<<<3196, 256, 0, stream>>>(vf, w_in, wbs, xb, ob, wfrag, S8);

    // L0: x0 = relu(bn(conv(vf)))                 -> xb
    conv_k<<<CBLK, 256, 0, stream>>>(xb, nbr, wfrag, rb, S8);
    apply_k<<<3125, 256, 0, stream>>>(rb, S8, g_in, b_in, nullptr, xb, nullptr);

    // L1: o = relu(bn(conv(x0)))                  -> ob
    conv_k<<<CBLK, 256, 0, stream>>>(xb, nbr, wfrag + FR, rb, S8 + SL);
    apply_k<<<3125, 256, 0, stream>>>(rb, S8 + SL, gs + 0, bs + 0, nullptr, ob, nullptr);

    // L2: x1 = relu(bn(conv(o)) + x0)             -> xb (in place resid)
    conv_k<<<CBLK, 256, 0, stream>>>(ob, nbr, wfrag + 2 * FR, rb, S8 + 2 * SL);
    apply_k<<<3125, 256, 0, stream>>>(rb, S8 + 2 * SL, gs + 16, bs + 16, xb, xb, nullptr);

    // L3: o = relu(bn(conv(x1)))                  -> ob
    conv_k<<<CBLK, 256, 0, stream>>>(xb, nbr, wfrag + 3 * FR, rb, S8 + 3 * SL);
    apply_k<<<3125, 256, 0, stream>>>(rb, S8 + 3 * SL, gs + 32, bs + 32, nullptr, ob, nullptr);

    // L4: out = relu(bn(conv(o)) + x1)            -> d_out (f32)
    conv_k<<<CBLK, 256, 0, stream>>>(ob, nbr, wfrag + 4 * FR, rb, S8 + 4 * SL);
    apply_k<<<3125, 256, 0, stream>>>(rb, S8 + 4 * SL, gs + 48, bs + 48, xb, nullptr, out);
}

// Round 17
// 150.847 us; speedup vs baseline: 1.1867x; 1.1867x over previous
//
#include <hip/hip_runtime.h>

#define N_TOT  400000
#define NTILE  25000        // N_TOT / 16 voxels per tile
#define NELEM  (N_TOT * 16)
#define CBLK   512          // persistent conv blocks (2 per CU)
#define GS     (CBLK * 4)   // wave grid stride (tiles)

typedef __attribute__((ext_vector_type(8))) short short8;
typedef __attribute__((ext_vector_type(4))) float f32x4;
typedef __attribute__((ext_vector_type(4))) unsigned short us4;

__device__ __forceinline__ unsigned short f2bf(float x) {
    unsigned int u = __float_as_uint(x);
    u += 0x7FFFu + ((u >> 16) & 1u);       // round-to-nearest-even
    return (unsigned short)(u >> 16);
}
__device__ __forceinline__ float bf2f(unsigned short h) {
    return __uint_as_float(((unsigned int)h) << 16);
}

// Merged prep: blocks 0..3124 cvt f32->bf16; 3125..3194 build W-fragments for
// all 5 layers x 14 k-pairs (fragment (lane,slot)->element: lane l slot j ->
// W[2p+(l>>5)][((l>>4)&1)*8+j][l&15], used as the MFMA A-operand after the
// operand swap); block 3195 zeroes the pad voxel (index N_TOT) in xb/ob and
// the 5 per-layer S8 atomic-partial slots (replay-safe reset each launch).
__global__ __launch_bounds__(256) void prep_k(const float* __restrict__ vf,
                                              const float* __restrict__ w_in,
                                              const float* __restrict__ wbs,
                                              unsigned short* __restrict__ xb,
                                              unsigned short* __restrict__ ob,
                                              unsigned short* __restrict__ wfrag,
                                              unsigned long long* __restrict__ S8) {
    int b = blockIdx.x;
    if (b < 3125) {
        int i = (b * 256 + threadIdx.x) * 8;
        f32x4 a = *reinterpret_cast<const f32x4*>(vf + i);
        f32x4 c = *reinterpret_cast<const f32x4*>(vf + i + 4);
        short8 o = { (short)f2bf(a[0]), (short)f2bf(a[1]), (short)f2bf(a[2]), (short)f2bf(a[3]),
                     (short)f2bf(c[0]), (short)f2bf(c[1]), (short)f2bf(c[2]), (short)f2bf(c[3]) };
        *reinterpret_cast<short8*>(xb + i) = o;
    } else if (b < 3195) {
        if (threadIdx.x >= 64) return;
        int wb = b - 3125;               // L*14 + p
        int L = wb / 14, p = wb % 14;
        int l = threadIdx.x;
        int g = l >> 4, col = l & 15;
        int k = 2 * p + (g >> 1);
        int cib = (g & 1) * 8;
        unsigned short v[8];
#pragma unroll
        for (int j = 0; j < 8; ++j) {
            float w = 0.f;
            if (k < 27) {
                int ci = cib + j;
                w = (L == 0) ? w_in[(k * 16 + ci) * 16 + col]
                             : wbs[(((L - 1) * 27 + k) * 16 + ci) * 16 + col];
            }
            v[j] = f2bf(w);
        }
        unsigned short* dst = wfrag + (size_t)(wb * 64 + l) * 8;
#pragma unroll
        for (int j = 0; j < 8; ++j) dst[j] = v[j];
    } else {
        if (threadIdx.x < 8) {
            us4 z = {0, 0, 0, 0};
            unsigned short* base = (threadIdx.x < 4) ? xb : ob;
            reinterpret_cast<us4*>(base + NELEM)[threadIdx.x & 3] = z;
        }
        for (int i = threadIdx.x; i < 5 * 8 * 32; i += 256) S8[i] = 0ull;
    }
}

// Persistent gather-MFMA conv, 3-stage decoupled pipeline (champion structure):
//   idx loads tile t+2S | gathers tile t+S | MFMA+store tile t.
// Operand swap: W = A-operand (registers), gathered features = B-operand ->
// each lane's 4 acc values are 4 contiguous CHANNELS of voxel rc -> single
// packed 8B store. Center (k=13) = identity (no load); invalid -> zero voxel
// at N_TOT (coalesced broadcast line). BN partials: per-channel lane
// accumulators, block-reduced, then 32 scaled-int64 atomicAdds (exact-
// commutative -> deterministic) into this layer's S8 slot. No reduce kernel.
#define IDX(I, tt)                                                              \
  {                                                                             \
    const int vv = (tt) * 16;                                                   \
    _Pragma("unroll")                                                           \
    for (int p = 0; p < 14; ++p) {                                              \
      int k = 2 * p + ksel;                                                     \
      if (k == 13)      I[p] = vv + rc;                                         \
      else if (k < 27)  I[p] = nbr[(size_t)k * N_TOT + vv + rc];                \
      else              I[p] = -1;                                              \
    }                                                                           \
  }

#define GAT(A, I)                                                               \
  {                                                                             \
    _Pragma("unroll")                                                           \
    for (int p = 0; p < 14; ++p) {                                              \
      int ci = I[p] < 0 ? N_TOT : I[p];                                         \
      A[p] = *reinterpret_cast<const short8*>(feats + ((size_t)ci << 4) + half);\
    }                                                                           \
  }

#define CMP(A, tt)                                                              \
  {                                                                             \
    f32x4 ac0 = {0.f, 0.f, 0.f, 0.f};                                           \
    f32x4 ac1 = {0.f, 0.f, 0.f, 0.f};                                           \
    _Pragma("unroll")                                                           \
    for (int p = 0; p < 14; p += 2) {                                           \
      ac0 = __builtin_amdgcn_mfma_f32_16x16x32_bf16(W[p],     A[p],     ac0, 0, 0, 0); \
      ac1 = __builtin_amdgcn_mfma_f32_16x16x32_bf16(W[p + 1], A[p + 1], ac1, 0, 0, 0); \
    }                                                                           \
    f32x4 acc = ac0 + ac1;                                                      \
    const int vv = (tt) * 16;                                                   \
    us4 pk = { f2bf(acc[0]), f2bf(acc[1]), f2bf(acc[2]), f2bf(acc[3]) };        \
    *reinterpret_cast<us4*>(raw + ((size_t)(vv + rc) * 16 + hi * 4)) = pk;      \
    _Pragma("unroll")                                                           \
    for (int i = 0; i < 4; ++i) {                                               \
      s_acc[i] += acc[i];                                                       \
      q_acc[i] += acc[i] * acc[i];                                              \
    }                                                                           \
  }

__global__ __launch_bounds__(256, 2) void conv_k(const unsigned short* __restrict__ feats,
                                                 const int* __restrict__ nbr,
                                                 const unsigned short* __restrict__ wfrag,
                                                 unsigned short* __restrict__ raw,
                                                 unsigned long long* __restrict__ S8) {
    __shared__ float red[128];

    const int lane = threadIdx.x & 63;
    const int wv   = threadIdx.x >> 6;
    const int hi   = lane >> 4;        // fragment k-block / output channel group
    const int rc   = lane & 15;        // voxel within tile
    const int half = (hi & 1) * 8;     // which 8 input channels this lane loads
    const int ksel = hi >> 1;          // which offset of the pair

    // loop-invariant W-fragments: 14 x short8 = 56 VGPRs, loaded once per wave
    short8 W[14];
#pragma unroll
    for (int p = 0; p < 14; ++p)
        W[p] = *reinterpret_cast<const short8*>(wfrag + (size_t)(p * 64 + lane) * 8);

    float s_acc[4] = {0.f, 0.f, 0.f, 0.f};
    float q_acc[4] = {0.f, 0.f, 0.f, 0.f};

    int I0[14], I1[14];
    short8 A0[14], A1[14];

    int t0 = blockIdx.x * 4 + wv;
    IDX(I0, t0);
    GAT(A0, I0);                       // one exposed stall at prologue
    int t1 = t0 + GS;
    if (t1 < NTILE) IDX(I1, t1);

    for (;;) {
        // invariant: A0 in flight for t0; I1 in flight/arrived for t1
        int t2 = t0 + 2 * GS;
        if (t2 < NTILE) IDX(I0, t2);
        if (t1 < NTILE) GAT(A1, I1);
        __builtin_amdgcn_sched_barrier(0);
        CMP(A0, t0);
        if (t1 >= NTILE) break;

        int t3 = t1 + 2 * GS;
        if (t3 < NTILE) IDX(I1, t3);
        if (t2 < NTILE) GAT(A0, I0);
        __builtin_amdgcn_sched_barrier(0);
        CMP(A1, t1);
        if (t2 >= NTILE) break;

        t0 = t2;
        t1 = t2 + GS;
    }

    // BN partials: lane (hi,rc) holds channels hi*4+i summed over its voxels;
    // reduce over rc within each 16-lane group, across waves via LDS, then 32
    // scaled-int64 atomics (8 shadow copies spread contention).
#pragma unroll
    for (int i = 0; i < 4; ++i) {
        s_acc[i] += __shfl_xor(s_acc[i], 1);  s_acc[i] += __shfl_xor(s_acc[i], 2);
        s_acc[i] += __shfl_xor(s_acc[i], 4);  s_acc[i] += __shfl_xor(s_acc[i], 8);
        q_acc[i] += __shfl_xor(q_acc[i], 1);  q_acc[i] += __shfl_xor(q_acc[i], 2);
        q_acc[i] += __shfl_xor(q_acc[i], 4);  q_acc[i] += __shfl_xor(q_acc[i], 8);
    }
    if (rc == 0) {
#pragma unroll
        for (int i = 0; i < 4; ++i) {
            red[wv * 32 + hi * 4 + i]      = s_acc[i];
            red[wv * 32 + 16 + hi * 4 + i] = q_acc[i];
        }
    }
    __syncthreads();
    if (threadIdx.x < 32) {
        float v = red[threadIdx.x] + red[32 + threadIdx.x] +
                  red[64 + threadIdx.x] + red[96 + threadIdx.x];
        long long qv = llrintf(v * (threadIdx.x < 16 ? 65536.0f : 16384.0f));
        atomicAdd(&S8[(blockIdx.x & 7) * 32 + threadIdx.x], (unsigned long long)qv);
    }
}

// BN finalize fused; sums the 8 S8 shadows inline, reads raw bf16 conv output,
// optional bf16 residual, writes bf16 features and/or f32 final output.
__global__ __launch_bounds__(256) void apply_k(const unsigned short* __restrict__ raw,
                                               const unsigned long long* __restrict__ S8,
                                               const float* __restrict__ gamma,
                                               const float* __restrict__ beta,
                                               const unsigned short* residb,
                                               unsigned short* bfout,
                                               float* f32out) {
    __shared__ float scs[16], shs[16];
    if (threadIdx.x < 16) {
        int c = threadIdx.x;
        long long ss = 0, qq = 0;
#pragma unroll
        for (int j = 0; j < 8; ++j) {
            ss += (long long)S8[j * 32 + c];
            qq += (long long)S8[j * 32 + 16 + c];
        }
        float s = (float)ss * (1.0f / 65536.0f);
        float q = (float)qq * (1.0f / 16384.0f);
        const float invN = 1.0f / (float)N_TOT;
        float m   = s * invN;
        float var = q * invN - m * m;
        float sc  = gamma[c] * rsqrtf(var + 1e-3f);
        scs[c] = sc;
        shs[c] = beta[c] - m * sc;
    }
    __syncthreads();
    int i = (blockIdx.x * 256 + threadIdx.x) * 8;
    int c0 = i & 8;                    // channels c0..c0+7
    short8 r8 = *reinterpret_cast<const short8*>(raw + i);
    float res[8] = {0, 0, 0, 0, 0, 0, 0, 0};
    if (residb) {
        short8 x8 = *reinterpret_cast<const short8*>(residb + i);
#pragma unroll
        for (int j = 0; j < 8; ++j) res[j] = bf2f((unsigned short)x8[j]);
    }
    float val[8];
#pragma unroll
    for (int j = 0; j < 8; ++j) {
        int c = c0 + j;
        val[j] = fmaxf(bf2f((unsigned short)r8[j]) * scs[c] + shs[c] + res[j], 0.f);
    }
    if (bfout) {
        short8 o = { (short)f2bf(val[0]), (short)f2bf(val[1]), (short)f2bf(val[2]), (short)f2bf(val[3]),
                     (short)f2bf(val[4]), (short)f2bf(val[5]), (short)f2bf(val[6]), (short)f2bf(val[7]) };
        *reinterpret_cast<short8*>(bfout + i) = o;
    }
    if (f32out) {
        f32x4 lo = { val[0], val[1], val[2], val[3] };
        f32x4 hi = { val[4], val[5], val[6], val[7] };
        *reinterpret_cast<f32x4*>(f32out + i)     = lo;
        *reinterpret_cast<f32x4*>(f32out + i + 4) = hi;
    }
}

extern "C" void kernel_launch(void* const* d_in, const int* in_sizes, int n_in,
                              void* d_out, int out_size, void* d_ws, size_t ws_size,
                              hipStream_t stream) {
    const float* vf   = (const float*)d_in[0];
    const int*   nbr  = (const int*)  d_in[1];
    const float* w_in = (const float*)d_in[2];
    const float* g_in = (const float*)d_in[3];
    const float* b_in = (const float*)d_in[4];
    const float* wbs  = (const float*)d_in[5];
    const float* gs   = (const float*)d_in[6];
    const float* bs   = (const float*)d_in[7];
    float* out = (float*)d_out;

    char* ws = (char*)d_ws;
    size_t off = 0;
    auto alloc = [&](size_t b) { char* p = ws + off; off += (b + 255) & ~(size_t)255; return p; };
    unsigned short*     wfrag = (unsigned short*)alloc((size_t)5 * 14 * 64 * 8 * 2);
    unsigned short*     xb    = (unsigned short*)alloc((size_t)(NELEM + 16) * 2);  // bf16 x (+zero voxel)
    unsigned short*     ob    = (unsigned short*)alloc((size_t)(NELEM + 16) * 2);  // bf16 o (+zero voxel)
    unsigned short*     rb    = (unsigned short*)alloc((size_t)NELEM * 2);         // bf16 raw conv out
    unsigned long long* S8    = (unsigned long long*)alloc((size_t)5 * 8 * 32 * 8);

    const int FR = 14 * 64 * 8;   // ushorts per layer of wfrag
    const int SL = 8 * 32;        // u64s per layer of S8

    prep_k<<<3196, 256, 0, stream>>>(vf, w_in, wbs, xb, ob, wfrag, S8);

    // L0: x0 = relu(bn(conv(vf)))                 -> xb
    conv_k<<<CBLK, 256, 0, stream>>>(xb, nbr, wfrag, rb, S8);
    apply_k<<<3125, 256, 0, stream>>>(rb, S8, g_in, b_in, nullptr, xb, nullptr);

    // L1: o = relu(bn(conv(x0)))                  -> ob
    conv_k<<<CBLK, 256, 0, stream>>>(xb, nbr, wfrag + FR, rb, S8 + SL);
    apply_k<<<3125, 256, 0, stream>>>(rb, S8 + SL, gs + 0, bs + 0, nullptr, ob, nullptr);

    // L2: x1 = relu(bn(conv(o)) + x0)             -> xb (in place resid)
    conv_k<<<CBLK, 256, 0, stream>>>(ob, nbr, wfrag + 2 * FR, rb, S8 + 2 * SL);
    apply_k<<<3125, 256, 0, stream>>>(rb, S8 + 2 * SL, gs + 16, bs + 16, xb, xb, nullptr);

    // L3: o = relu(bn(conv(x1)))                  -> ob
    conv_k<<<CBLK, 256, 0, stream>>>(xb, nbr, wfrag + 3 * FR, rb, S8 + 3 * SL);
    apply_k<<<3125, 256, 0, stream>>>(rb, S8 + 3 * SL, gs + 32, bs + 32, nullptr, ob, nullptr);

    // L4: out = relu(bn(conv(o)) + x1)            -> d_out (f32)
    conv_k<<<CBLK, 256, 0, stream>>>(ob, nbr, wfrag + 4 * FR, rb, S8 + 4 * SL);
    apply_k<<<3125, 256, 0, stream>>>(rb, S8 + 4 * SL, gs + 48, bs + 48, xb, nullptr, out);
}